// Round 2
// baseline (1857.060 us; speedup 1.0000x reference)
//
#include <hip/hip_runtime.h>
#include <cfloat>
#include <math.h>

#define B_ 8
#define N_ 4096
#define F_ 64
#define O_ 64
#define K_ 20
#define CAND 24
#define TI 32
#define TJ 128

// ---------------- K1: squared norms ----------------
__global__ __launch_bounds__(256) void sq_kernel(const float* __restrict__ x,
                                                 float* __restrict__ sq) {
  int p = blockIdx.x * 256 + threadIdx.x;  // 0..B*N-1
  const float4* xr = (const float4*)(x + (size_t)p * F_);
  float a0 = 0.f, a1 = 0.f, a2 = 0.f, a3 = 0.f;
#pragma unroll
  for (int f = 0; f < 16; ++f) {
    float4 v = xr[f];
    a0 += v.x * v.x; a1 += v.y * v.y; a2 += v.z * v.z; a3 += v.w * v.w;
  }
  sq[p] = (a0 + a1) + (a2 + a3);
}

// ---------------- K2: kNN phase 1 — f32 top-24 candidates ----------------
struct SmemA { float xj[TJ][68]; float sqj[TJ]; };             // 35,328 B
struct SmemM { float md[TI][8][CAND]; int mi[TI][8][CAND]; };  // 49,152 B

__global__ __launch_bounds__(256) void knn_kernel(const float* __restrict__ x,
                                                  const float* __restrict__ sq,
                                                  int* __restrict__ cand) {
  __shared__ union USm { SmemA a; SmemM m; } S;

  const int b = blockIdx.x >> 7;        // 128 tiles per batch
  const int tile = blockIdx.x & 127;
  const int i_local = threadIdx.x >> 3; // 0..31
  const int j_slot = threadIdx.x & 7;   // 0..7
  const int i = tile * TI + i_local;
  const int g = b * N_ + i;

  // pin x_i in registers (64 VGPRs)
  float4 xi[16];
  {
    const float4* xr = (const float4*)(x + (size_t)g * F_);
#pragma unroll
    for (int f = 0; f < 16; ++f) xi[f] = xr[f];
  }
  const float sqi = sq[g];

  float d[CAND]; int id[CAND];
#pragma unroll
  for (int k = 0; k < CAND; ++k) { d[k] = FLT_MAX; id[k] = -1; }

  for (int jt = 0; jt < N_; jt += TJ) {
    __syncthreads();  // protect previous tile's readers
    // cooperative coalesced stage of 128 x-rows into padded LDS
    {
      const float4* src = (const float4*)(x + ((size_t)b * N_ + jt) * F_);
#pragma unroll
      for (int u = 0; u < 8; ++u) {
        int idx = threadIdx.x + u * 256;     // 0..2047
        int jr = idx >> 4, ff = idx & 15;
        ((float4*)&S.a.xj[jr][0])[ff] = src[idx];
      }
      if (threadIdx.x < TJ) S.a.sqj[threadIdx.x] = sq[b * N_ + jt + threadIdx.x];
    }
    __syncthreads();

#pragma unroll
    for (int u = 0; u < 16; ++u) {
      const int jl = j_slot + (u << 3);      // 0..127, 8-way broadcast reads
      const float4* xjr = (const float4*)&S.a.xj[jl][0];
      float c0 = 0.f, c1 = 0.f, c2 = 0.f, c3 = 0.f;
#pragma unroll
      for (int ff = 0; ff < 16; ++ff) {
        float4 v = xjr[ff];
        c0 += xi[ff].x * v.x; c1 += xi[ff].y * v.y;
        c2 += xi[ff].z * v.z; c3 += xi[ff].w * v.w;
      }
      float dot = (c0 + c1) + (c2 + c3);
      int j = jt + jl;
      float cd = sqi + S.a.sqj[jl] - 2.f * dot;
      if (j == i) cd = FLT_MAX;  // exclude self (FLT_MAX never inserts)
      if (cd < d[CAND - 1]) {
        // branch-free sorted insert (ascending)
#pragma unroll
        for (int k = CAND - 1; k >= 1; --k) {
          bool sh = cd < d[k - 1];
          bool ins = cd < d[k];
          float nd = sh ? d[k - 1] : (ins ? cd : d[k]);
          int ni = sh ? id[k - 1] : (ins ? j : id[k]);
          d[k] = nd; id[k] = ni;
        }
        if (cd < d[0]) { d[0] = cd; id[0] = j; }
      }
    }
  }

  __syncthreads();  // done with xj region; alias to merge buffers
#pragma unroll
  for (int k = 0; k < CAND; ++k) {
    S.m.md[i_local][j_slot][k] = d[k];
    S.m.mi[i_local][j_slot][k] = id[k];
  }
  __syncthreads();

  // 8-way merge of sorted lists; one thread per row; emit 24 candidates
  if (threadIdx.x < TI) {
    const int il = threadIdx.x;
    int* crow = cand + (size_t)(b * N_ + tile * TI + il) * CAND;
    int p0 = 0, p1 = 0, p2 = 0, p3 = 0, p4 = 0, p5 = 0, p6 = 0, p7 = 0;
    for (int k = 0; k < CAND; ++k) {
      float hv = S.m.md[il][0][p0]; int sm = 0; int pm = p0;
      float t;
      t = S.m.md[il][1][p1]; if (t < hv) { hv = t; sm = 1; pm = p1; }
      t = S.m.md[il][2][p2]; if (t < hv) { hv = t; sm = 2; pm = p2; }
      t = S.m.md[il][3][p3]; if (t < hv) { hv = t; sm = 3; pm = p3; }
      t = S.m.md[il][4][p4]; if (t < hv) { hv = t; sm = 4; pm = p4; }
      t = S.m.md[il][5][p5]; if (t < hv) { hv = t; sm = 5; pm = p5; }
      t = S.m.md[il][6][p6]; if (t < hv) { hv = t; sm = 6; pm = p6; }
      t = S.m.md[il][7][p7]; if (t < hv) { hv = t; sm = 7; pm = p7; }
      crow[k] = S.m.mi[il][sm][pm];
      p0 += (sm == 0); p1 += (sm == 1); p2 += (sm == 2); p3 += (sm == 3);
      p4 += (sm == 4); p5 += (sm == 5); p6 += (sm == 6); p7 += (sm == 7);
    }
  }
}

// ---------------- K2b: kNN phase 2 — fp64 refine of 24 candidates ----------------
__global__ __launch_bounds__(256) void refine_kernel(const float* __restrict__ x,
                                                     const int* __restrict__ cand,
                                                     int* __restrict__ nn) {
  const int w = threadIdx.x >> 6, lane = threadIdx.x & 63;
  const int row = blockIdx.x * 4 + w;
  const int b = row >> 12;
  const double xif = (double)x[(size_t)row * F_ + lane];  // lane = feature
  const int* crow = cand + (size_t)row * CAND;

  double cd[CAND]; int cj[CAND];
  double dm = 0.0; int jm = -1;
#pragma unroll
  for (int m = 0; m < CAND; ++m) {
    int j = crow[m];  // wave-uniform
    double diff = xif - (double)x[((size_t)(b << 12) + j) * F_ + lane];
    double s = diff * diff;
#pragma unroll
    for (int off = 32; off >= 1; off >>= 1) s += __shfl_xor(s, off, 64);
    cd[m] = s; cj[m] = j;
    if (lane == m) { dm = s; jm = j; }  // compile-time m vs runtime lane: no dyn index
  }
  if (lane < CAND) {
    int rank = 0;
#pragma unroll
    for (int m = 0; m < CAND; ++m)
      rank += (cd[m] < dm) || (cd[m] == dm && cj[m] < jm);
    if (rank < K_) nn[(size_t)row * K_ + rank] = jm;
  }
}

// ---------------- K3: A = X(W1-W2)^T, C = X W2^T ----------------
__global__ __launch_bounds__(256) void feat_kernel(const float* __restrict__ x,
                                                   const float* __restrict__ W,
                                                   float* __restrict__ A,
                                                   float* __restrict__ C) {
  int gid = blockIdx.x * 256 + threadIdx.x;
  int n = gid >> 7;
  int o = gid & 127;  // wave-uniform branch: lanes 0..63 all same half
  const float4* xr = (const float4*)(x + (size_t)n * F_);
  float a0 = 0.f, a1 = 0.f, a2 = 0.f, a3 = 0.f;
  if (o < O_) {
    const float4* w1 = (const float4*)(W + (size_t)o * 128);
    const float4* w2 = w1 + 16;
#pragma unroll
    for (int f = 0; f < 16; ++f) {
      float4 xv = xr[f]; float4 u = w1[f]; float4 v = w2[f];
      a0 += xv.x * (u.x - v.x); a1 += xv.y * (u.y - v.y);
      a2 += xv.z * (u.z - v.z); a3 += xv.w * (u.w - v.w);
    }
    A[(size_t)n * O_ + o] = (a0 + a1) + (a2 + a3);
  } else {
    const float4* w2 = (const float4*)(W + (size_t)(o - O_) * 128 + 64);
#pragma unroll
    for (int f = 0; f < 16; ++f) {
      float4 xv = xr[f]; float4 v = w2[f];
      a0 += xv.x * v.x; a1 += xv.y * v.y; a2 += xv.z * v.z; a3 += xv.w * v.w;
    }
    C[(size_t)n * O_ + (o - O_)] = (a0 + a1) + (a2 + a3);
  }
}

// ---------------- K4: neighbor gather -> P/Q + BN partial sums ----------------
__global__ __launch_bounds__(256) void gather_kernel(const int* __restrict__ nn,
                                                     const float* __restrict__ A,
                                                     const float* __restrict__ C,
                                                     const float* __restrict__ bias,
                                                     float* __restrict__ P,
                                                     float* __restrict__ Q,
                                                     float* __restrict__ sums) {
  __shared__ float red[4][2][O_];
  int w = threadIdx.x >> 6;   // wave = row within block
  int o = threadIdx.x & 63;   // channel
  int rowg = blockIdx.x * 4 + w;
  int bb = rowg >> 12;
  const int* nrow = nn + (size_t)rowg * K_;
  float a = A[(size_t)rowg * O_ + o] + bias[o];
  float mx = -FLT_MAX, mn = FLT_MAX, s1 = 0.f, s2 = 0.f;
  for (int k = 0; k < K_; ++k) {
    int j = nrow[k];  // wave-broadcast scalar load
    float c = C[((size_t)(bb << 12) + j) * O_ + o];  // coalesced 256B row
    mx = fmaxf(mx, c); mn = fminf(mn, c); s1 += c; s2 += c * c;
  }
  P[(size_t)rowg * O_ + o] = a + mx;   // max_k h
  Q[(size_t)rowg * O_ + o] = a + mn;   // min_k h
  red[w][0][o] = 20.f * a + s1;
  red[w][1][o] = 20.f * a * a + 2.f * a * s1 + s2;
  __syncthreads();
  if (w == 0) {
    float ts = red[0][0][o] + red[1][0][o] + red[2][0][o] + red[3][0][o];
    float tq = red[0][1][o] + red[1][1][o] + red[2][1][o] + red[3][1][o];
    atomicAdd(&sums[o], ts);
    atomicAdd(&sums[O_ + o], tq);
  }
}

// ---------------- K5: finalize BN stats ----------------
__global__ void stats_kernel(const float* __restrict__ sums,
                             const float* __restrict__ gamma,
                             const float* __restrict__ beta,
                             float* __restrict__ sb) {
  int o = threadIdx.x;
  const float cnt = (float)B_ * (float)N_ * (float)K_;
  float mean = sums[o] / cnt;
  float var = sums[O_ + o] / cnt - mean * mean;
  float s = gamma[o] / sqrtf(var + 1e-5f);
  sb[o] = s;
  sb[O_ + o] = beta[o] - mean * s;
}

// ---------------- K6: normalize + relu (max over k already folded) ----------------
__global__ __launch_bounds__(256) void out_kernel(const float* __restrict__ P,
                                                  const float* __restrict__ Q,
                                                  const float* __restrict__ sb,
                                                  float* __restrict__ out) {
  int gid = blockIdx.x * 256 + threadIdx.x;
  int o = gid & 63;
  float s = sb[o], base = sb[O_ + o];
  float h = (s >= 0.f) ? P[gid] : Q[gid];  // affine monotone: pick extreme
  float z = h * s + base;
  out[gid] = z > 0.f ? z : 0.f;
}

extern "C" void kernel_launch(void* const* d_in, const int* in_sizes, int n_in,
                              void* d_out, int out_size, void* d_ws, size_t ws_size,
                              hipStream_t stream) {
  const float* x     = (const float*)d_in[0];
  const float* W     = (const float*)d_in[1];
  const float* bias  = (const float*)d_in[2];
  const float* gamma = (const float*)d_in[3];
  const float* beta  = (const float*)d_in[4];
  float* out = (float*)d_out;

  char* ws = (char*)d_ws;
  size_t off = 0;
  auto alloc = [&](size_t bytes) -> void* {
    void* p = ws + off;
    off += (bytes + 255) & ~(size_t)255;
    return p;
  };
  float* sq   = (float*)alloc(sizeof(float) * (size_t)B_ * N_);
  int*   cand = (int*)  alloc(sizeof(int)   * (size_t)B_ * N_ * CAND);
  int*   nn   = (int*)  alloc(sizeof(int)   * (size_t)B_ * N_ * K_);
  float* A    = (float*)alloc(sizeof(float) * (size_t)B_ * N_ * O_);
  float* C    = (float*)alloc(sizeof(float) * (size_t)B_ * N_ * O_);
  float* P    = (float*)alloc(sizeof(float) * (size_t)B_ * N_ * O_);
  float* Q    = (float*)alloc(sizeof(float) * (size_t)B_ * N_ * O_);
  float* sums = (float*)alloc(sizeof(float) * 2 * O_);
  float* sb   = (float*)alloc(sizeof(float) * 2 * O_);

  hipMemsetAsync(sums, 0, sizeof(float) * 2 * O_, stream);

  sq_kernel    <<<(B_ * N_) / 256, 256, 0, stream>>>(x, sq);
  knn_kernel   <<<B_ * (N_ / TI), 256, 0, stream>>>(x, sq, cand);
  refine_kernel<<<(B_ * N_) / 4, 256, 0, stream>>>(x, cand, nn);
  feat_kernel  <<<(B_ * N_ * 128) / 256, 256, 0, stream>>>(x, W, A, C);
  gather_kernel<<<(B_ * N_) / 4, 256, 0, stream>>>(nn, A, C, bias, P, Q, sums);
  stats_kernel <<<1, 64, 0, stream>>>(sums, gamma, beta, sb);
  out_kernel   <<<(B_ * N_ * O_) / 256, 256, 0, stream>>>(P, Q, sb, out);
}

// Round 3
// 1566.920 us; speedup vs baseline: 1.1852x; 1.1852x over previous
//
#include <hip/hip_runtime.h>
#include <cfloat>
#include <math.h>

#define B_ 8
#define N_ 4096
#define F_ 64
#define O_ 64
#define K_ 20
#define CAND 24
#define ITILE 64      // i-rows per block
#define JCH 128       // j-chunk per iteration
#define BSTR 80       // ushort stride of staged bf16 rows (160 B, 16B-aligned)
#define DSTR 132      // dword stride of d2 tile (16B-aligned)

typedef __attribute__((ext_vector_type(8))) short bf16x8;
typedef __attribute__((ext_vector_type(4))) float f32x4;

__device__ __forceinline__ ushort f2bf(float f) {
  unsigned u = __float_as_uint(f);
  u += 0x7FFF + ((u >> 16) & 1);   // round-to-nearest-even
  return (ushort)(u >> 16);
}
__device__ __forceinline__ float bf2f(ushort h) {
  return __uint_as_float(((unsigned)h) << 16);
}

// ---------------- K0: split x into bf16 hi/lo ----------------
__global__ __launch_bounds__(256) void cvt_kernel(const float* __restrict__ x,
                                                  ushort* __restrict__ xhi,
                                                  ushort* __restrict__ xlo) {
  int p = blockIdx.x * 256 + threadIdx.x;  // one float4 per thread
  float4 v = ((const float4*)x)[p];
  ushort h0 = f2bf(v.x), h1 = f2bf(v.y), h2 = f2bf(v.z), h3 = f2bf(v.w);
  ushort l0 = f2bf(v.x - bf2f(h0)), l1 = f2bf(v.y - bf2f(h1));
  ushort l2 = f2bf(v.z - bf2f(h2)), l3 = f2bf(v.w - bf2f(h3));
  ((ushort4*)xhi)[p] = make_ushort4(h0, h1, h2, h3);
  ((ushort4*)xlo)[p] = make_ushort4(l0, l1, l2, l3);
}

// ---------------- K1: squared norms (fp32) ----------------
__global__ __launch_bounds__(256) void sq_kernel(const float* __restrict__ x,
                                                 float* __restrict__ sq) {
  int p = blockIdx.x * 256 + threadIdx.x;
  const float4* xr = (const float4*)(x + (size_t)p * F_);
  float a0 = 0.f, a1 = 0.f, a2 = 0.f, a3 = 0.f;
#pragma unroll
  for (int f = 0; f < 16; ++f) {
    float4 v = xr[f];
    a0 += v.x * v.x; a1 += v.y * v.y; a2 += v.z * v.z; a3 += v.w * v.w;
  }
  sq[p] = (a0 + a1) + (a2 + a3);
}

// ---------------- K2: kNN phase 1 — MFMA distances + top-24 ----------------
struct KS_s {
  ushort bhi[JCH][BSTR];    // 20480 B
  ushort blo[JCH][BSTR];    // 20480 B
  float sqj[JCH];           // 512 B
  float d2[ITILE][DSTR];    // 33792 B
};
struct KS_m {
  float md[ITILE][4][CAND];
  int   mi[ITILE][4][CAND]; // 49152 B total
};

__global__ __launch_bounds__(256) void knn_kernel(const ushort* __restrict__ xhi,
                                                  const ushort* __restrict__ xlo,
                                                  const float* __restrict__ sq,
                                                  int* __restrict__ cand) {
  __shared__ union { KS_s s; KS_m m; } S;

  const int b = blockIdx.x >> 6;        // 64 i-tiles per batch
  const int itile = blockIdx.x & 63;
  const int ib = itile * ITILE;         // batch-local i base
  const int w = threadIdx.x >> 6;       // wave 0..3
  const int lane = threadIdx.x & 63;
  const int hq = lane >> 4;             // quad 0..3
  const int lm = lane & 15;

  // A-fragments: wave covers i rows ib + w*16 + m (m = lane&15), K=64 in 2 halves
  bf16x8 ahi[2], alo[2];
  {
    const size_t rb = ((size_t)b * N_ + ib + w * 16 + lm) * F_ + hq * 8;
    ahi[0] = *(const bf16x8*)(xhi + rb);
    ahi[1] = *(const bf16x8*)(xhi + rb + 32);
    alo[0] = *(const bf16x8*)(xlo + rb);
    alo[1] = *(const bf16x8*)(xlo + rb + 32);
  }
  // sqi per C-reg r: tile row = hq*4 + r
  float sqi[4];
#pragma unroll
  for (int r = 0; r < 4; ++r) sqi[r] = sq[b * N_ + ib + w * 16 + hq * 4 + r];

  const int selrow = threadIdx.x >> 2;  // 0..63
  const int selslot = threadIdx.x & 3;  // 0..3

  float d[CAND]; int id[CAND];
#pragma unroll
  for (int k = 0; k < CAND; ++k) { d[k] = FLT_MAX; id[k] = -1; }

  for (int jt = 0; jt < N_; jt += JCH) {
    __syncthreads();  // selection of previous iter done
    // ---- stage 128 j-rows (hi+lo) + sqj into LDS, coalesced ----
    {
#pragma unroll
      for (int u = 0; u < 4; ++u) {
        int idx = threadIdx.x + u * 256;          // 0..1023
        int jr = idx >> 3, fc = (idx & 7) * 8;    // row, feature offset
        const size_t src = ((size_t)b * N_ + jt + jr) * F_ + fc;
        *(bf16x8*)&S.s.bhi[jr][fc] = *(const bf16x8*)(xhi + src);
        *(bf16x8*)&S.s.blo[jr][fc] = *(const bf16x8*)(xlo + src);
      }
      if (threadIdx.x < JCH) S.s.sqj[threadIdx.x] = sq[b * N_ + jt + threadIdx.x];
    }
    __syncthreads();

    // ---- MFMA: 8 j-subtiles of 16, write d2 tile ----
#pragma unroll
    for (int n0 = 0; n0 < 8; ++n0) {
      const ushort* bh = &S.s.bhi[n0 * 16 + lm][hq * 8];
      const ushort* bl = &S.s.blo[n0 * 16 + lm][hq * 8];
      bf16x8 bh0 = *(const bf16x8*)(bh);
      bf16x8 bh1 = *(const bf16x8*)(bh + 32);
      bf16x8 bl0 = *(const bf16x8*)(bl);
      bf16x8 bl1 = *(const bf16x8*)(bl + 32);
      f32x4 c = {0.f, 0.f, 0.f, 0.f};
      c = __builtin_amdgcn_mfma_f32_16x16x32_bf16(alo[0], bh0, c, 0, 0, 0);
      c = __builtin_amdgcn_mfma_f32_16x16x32_bf16(alo[1], bh1, c, 0, 0, 0);
      c = __builtin_amdgcn_mfma_f32_16x16x32_bf16(ahi[0], bl0, c, 0, 0, 0);
      c = __builtin_amdgcn_mfma_f32_16x16x32_bf16(ahi[1], bl1, c, 0, 0, 0);
      c = __builtin_amdgcn_mfma_f32_16x16x32_bf16(ahi[0], bh0, c, 0, 0, 0);
      c = __builtin_amdgcn_mfma_f32_16x16x32_bf16(ahi[1], bh1, c, 0, 0, 0);
      const float sqjv = S.s.sqj[n0 * 16 + lm];
      const int jg = jt + n0 * 16 + lm;
#pragma unroll
      for (int r = 0; r < 4; ++r) {
        const int ig = ib + w * 16 + hq * 4 + r;
        float dd = sqi[r] + sqjv - 2.f * c[r];
        if (ig == jg) dd = FLT_MAX;  // exclude self
        S.s.d2[w * 16 + hq * 4 + r][n0 * 16 + lm] = dd;
      }
    }
    __syncthreads();

    // ---- selection: 4 threads per row, 32 j's each ----
    {
      const float* dr = &S.s.d2[selrow][selslot * 32];
#pragma unroll
      for (int u = 0; u < 8; ++u) {
        float4 v = *(const float4*)(dr + u * 4);
#pragma unroll
        for (int e = 0; e < 4; ++e) {
          float cd = (e == 0) ? v.x : (e == 1) ? v.y : (e == 2) ? v.z : v.w;
          int j = jt + selslot * 32 + u * 4 + e;
          if (cd < d[CAND - 1]) {
#pragma unroll
            for (int k = CAND - 1; k >= 1; --k) {
              bool sh = cd < d[k - 1];
              bool ins = cd < d[k];
              float nd = sh ? d[k - 1] : (ins ? cd : d[k]);
              int ni = sh ? id[k - 1] : (ins ? j : id[k]);
              d[k] = nd; id[k] = ni;
            }
            if (cd < d[0]) { d[0] = cd; id[0] = j; }
          }
        }
      }
    }
  }

  __syncthreads();  // d2/bstage dead; alias to merge buffers
#pragma unroll
  for (int k = 0; k < CAND; ++k) {
    S.m.md[selrow][selslot][k] = d[k];
    S.m.mi[selrow][selslot][k] = id[k];
  }
  __syncthreads();

  // 4-way merge of sorted lists; one thread per row; emit 24 candidates
  if (threadIdx.x < ITILE) {
    const int il = threadIdx.x;
    int* crow = cand + (size_t)(b * N_ + ib + il) * CAND;
    int p0 = 0, p1 = 0, p2 = 0, p3 = 0;
    for (int k = 0; k < CAND; ++k) {
      float hv = S.m.md[il][0][p0]; int sm = 0; int pm = p0;
      float t;
      t = S.m.md[il][1][p1]; if (t < hv) { hv = t; sm = 1; pm = p1; }
      t = S.m.md[il][2][p2]; if (t < hv) { hv = t; sm = 2; pm = p2; }
      t = S.m.md[il][3][p3]; if (t < hv) { hv = t; sm = 3; pm = p3; }
      crow[k] = S.m.mi[il][sm][pm];
      p0 += (sm == 0); p1 += (sm == 1); p2 += (sm == 2); p3 += (sm == 3);
    }
  }
}

// ---------------- K2b: kNN phase 2 — fp64 refine of 24 candidates ----------------
__global__ __launch_bounds__(256) void refine_kernel(const float* __restrict__ x,
                                                     const int* __restrict__ cand,
                                                     int* __restrict__ nn) {
  const int w = threadIdx.x >> 6, lane = threadIdx.x & 63;
  const int row = blockIdx.x * 4 + w;
  const int b = row >> 12;
  const double xif = (double)x[(size_t)row * F_ + lane];  // lane = feature
  const int* crow = cand + (size_t)row * CAND;

  double cd[CAND]; int cj[CAND];
  double dm = 0.0; int jm = -1;
#pragma unroll
  for (int m = 0; m < CAND; ++m) {
    int j = crow[m];  // wave-uniform
    double diff = xif - (double)x[((size_t)(b << 12) + j) * F_ + lane];
    double s = diff * diff;
#pragma unroll
    for (int off = 32; off >= 1; off >>= 1) s += __shfl_xor(s, off, 64);
    cd[m] = s; cj[m] = j;
    if (lane == m) { dm = s; jm = j; }
  }
  if (lane < CAND) {
    int rank = 0;
#pragma unroll
    for (int m = 0; m < CAND; ++m)
      rank += (cd[m] < dm) || (cd[m] == dm && cj[m] < jm);
    if (rank < K_) nn[(size_t)row * K_ + rank] = jm;
  }
}

// ---------------- K3: A = X(W1-W2)^T, C = X W2^T ----------------
__global__ __launch_bounds__(256) void feat_kernel(const float* __restrict__ x,
                                                   const float* __restrict__ W,
                                                   float* __restrict__ A,
                                                   float* __restrict__ C) {
  int gid = blockIdx.x * 256 + threadIdx.x;
  int n = gid >> 7;
  int o = gid & 127;
  const float4* xr = (const float4*)(x + (size_t)n * F_);
  float a0 = 0.f, a1 = 0.f, a2 = 0.f, a3 = 0.f;
  if (o < O_) {
    const float4* w1 = (const float4*)(W + (size_t)o * 128);
    const float4* w2 = w1 + 16;
#pragma unroll
    for (int f = 0; f < 16; ++f) {
      float4 xv = xr[f]; float4 u = w1[f]; float4 v = w2[f];
      a0 += xv.x * (u.x - v.x); a1 += xv.y * (u.y - v.y);
      a2 += xv.z * (u.z - v.z); a3 += xv.w * (u.w - v.w);
    }
    A[(size_t)n * O_ + o] = (a0 + a1) + (a2 + a3);
  } else {
    const float4* w2 = (const float4*)(W + (size_t)(o - O_) * 128 + 64);
#pragma unroll
    for (int f = 0; f < 16; ++f) {
      float4 xv = xr[f]; float4 v = w2[f];
      a0 += xv.x * v.x; a1 += xv.y * v.y; a2 += xv.z * v.z; a3 += xv.w * v.w;
    }
    C[(size_t)n * O_ + (o - O_)] = (a0 + a1) + (a2 + a3);
  }
}

// ---------------- K4: neighbor gather -> P/Q + BN partial sums ----------------
__global__ __launch_bounds__(256) void gather_kernel(const int* __restrict__ nn,
                                                     const float* __restrict__ A,
                                                     const float* __restrict__ C,
                                                     const float* __restrict__ bias,
                                                     float* __restrict__ P,
                                                     float* __restrict__ Q,
                                                     float* __restrict__ sums) {
  __shared__ float red[4][2][O_];
  int w = threadIdx.x >> 6;
  int o = threadIdx.x & 63;
  int rowg = blockIdx.x * 4 + w;
  int bb = rowg >> 12;
  const int* nrow = nn + (size_t)rowg * K_;
  float a = A[(size_t)rowg * O_ + o] + bias[o];
  float mx = -FLT_MAX, mn = FLT_MAX, s1 = 0.f, s2 = 0.f;
  for (int k = 0; k < K_; ++k) {
    int j = nrow[k];
    float c = C[((size_t)(bb << 12) + j) * O_ + o];
    mx = fmaxf(mx, c); mn = fminf(mn, c); s1 += c; s2 += c * c;
  }
  P[(size_t)rowg * O_ + o] = a + mx;
  Q[(size_t)rowg * O_ + o] = a + mn;
  red[w][0][o] = 20.f * a + s1;
  red[w][1][o] = 20.f * a * a + 2.f * a * s1 + s2;
  __syncthreads();
  if (w == 0) {
    float ts = red[0][0][o] + red[1][0][o] + red[2][0][o] + red[3][0][o];
    float tq = red[0][1][o] + red[1][1][o] + red[2][1][o] + red[3][1][o];
    atomicAdd(&sums[o], ts);
    atomicAdd(&sums[O_ + o], tq);
  }
}

// ---------------- K5: finalize BN stats ----------------
__global__ void stats_kernel(const float* __restrict__ sums,
                             const float* __restrict__ gamma,
                             const float* __restrict__ beta,
                             float* __restrict__ sb) {
  int o = threadIdx.x;
  const float cnt = (float)B_ * (float)N_ * (float)K_;
  float mean = sums[o] / cnt;
  float var = sums[O_ + o] / cnt - mean * mean;
  float s = gamma[o] / sqrtf(var + 1e-5f);
  sb[o] = s;
  sb[O_ + o] = beta[o] - mean * s;
}

// ---------------- K6: normalize + relu ----------------
__global__ __launch_bounds__(256) void out_kernel(const float* __restrict__ P,
                                                  const float* __restrict__ Q,
                                                  const float* __restrict__ sb,
                                                  float* __restrict__ out) {
  int gid = blockIdx.x * 256 + threadIdx.x;
  int o = gid & 63;
  float s = sb[o], base = sb[O_ + o];
  float h = (s >= 0.f) ? P[gid] : Q[gid];
  float z = h * s + base;
  out[gid] = z > 0.f ? z : 0.f;
}

extern "C" void kernel_launch(void* const* d_in, const int* in_sizes, int n_in,
                              void* d_out, int out_size, void* d_ws, size_t ws_size,
                              hipStream_t stream) {
  const float* x     = (const float*)d_in[0];
  const float* W     = (const float*)d_in[1];
  const float* bias  = (const float*)d_in[2];
  const float* gamma = (const float*)d_in[3];
  const float* beta  = (const float*)d_in[4];
  float* out = (float*)d_out;

  char* ws = (char*)d_ws;
  size_t off = 0;
  auto alloc = [&](size_t bytes) -> void* {
    void* p = ws + off;
    off += (bytes + 255) & ~(size_t)255;
    return p;
  };
  ushort* xhi = (ushort*)alloc(sizeof(ushort) * (size_t)B_ * N_ * F_);
  ushort* xlo = (ushort*)alloc(sizeof(ushort) * (size_t)B_ * N_ * F_);
  float* sq   = (float*)alloc(sizeof(float) * (size_t)B_ * N_);
  int*   cand = (int*)  alloc(sizeof(int)   * (size_t)B_ * N_ * CAND);
  int*   nn   = (int*)  alloc(sizeof(int)   * (size_t)B_ * N_ * K_);
  float* A    = (float*)alloc(sizeof(float) * (size_t)B_ * N_ * O_);
  float* C    = (float*)alloc(sizeof(float) * (size_t)B_ * N_ * O_);
  float* P    = (float*)alloc(sizeof(float) * (size_t)B_ * N_ * O_);
  float* Q    = (float*)alloc(sizeof(float) * (size_t)B_ * N_ * O_);
  float* sums = (float*)alloc(sizeof(float) * 2 * O_);
  float* sb   = (float*)alloc(sizeof(float) * 2 * O_);

  hipMemsetAsync(sums, 0, sizeof(float) * 2 * O_, stream);

  cvt_kernel   <<<(B_ * N_ * F_ / 4) / 256, 256, 0, stream>>>(x, xhi, xlo);
  sq_kernel    <<<(B_ * N_) / 256, 256, 0, stream>>>(x, sq);
  knn_kernel   <<<B_ * (N_ / ITILE), 256, 0, stream>>>(xhi, xlo, sq, cand);
  refine_kernel<<<(B_ * N_) / 4, 256, 0, stream>>>(x, cand, nn);
  feat_kernel  <<<(B_ * N_ * 128) / 256, 256, 0, stream>>>(x, W, A, C);
  gather_kernel<<<(B_ * N_) / 4, 256, 0, stream>>>(nn, A, C, bias, P, Q, sums);
  stats_kernel <<<1, 64, 0, stream>>>(sums, gamma, beta, sb);
  out_kernel   <<<(B_ * N_ * O_) / 256, 256, 0, stream>>>(P, Q, sb, out);
}

// Round 4
// 547.701 us; speedup vs baseline: 3.3906x; 2.8609x over previous
//
#include <hip/hip_runtime.h>
#include <cfloat>
#include <math.h>

#define B_ 8
#define N_ 4096
#define F_ 64
#define O_ 64
#define K_ 20
#define CAND 24
#define ITILE 64      // i-rows per block
#define JCH 128       // j-chunk per iteration
#define QSTR 133      // rowq stride in floats (5 mod 32 -> 2-way banks)

typedef __attribute__((ext_vector_type(8))) short bf16x8;
typedef __attribute__((ext_vector_type(4))) float f32x4;

__device__ __forceinline__ ushort f2bf(float f) {
  unsigned u = __float_as_uint(f);
  u += 0x7FFF + ((u >> 16) & 1);   // round-to-nearest-even
  return (ushort)(u >> 16);
}
__device__ __forceinline__ float bf2f(ushort h) {
  return __uint_as_float(((unsigned)h) << 16);
}

// ---------------- K0: split x into bf16 hi/lo ----------------
__global__ __launch_bounds__(256) void cvt_kernel(const float* __restrict__ x,
                                                  ushort* __restrict__ xhi,
                                                  ushort* __restrict__ xlo) {
  int p = blockIdx.x * 256 + threadIdx.x;
  float4 v = ((const float4*)x)[p];
  ushort h0 = f2bf(v.x), h1 = f2bf(v.y), h2 = f2bf(v.z), h3 = f2bf(v.w);
  ushort l0 = f2bf(v.x - bf2f(h0)), l1 = f2bf(v.y - bf2f(h1));
  ushort l2 = f2bf(v.z - bf2f(h2)), l3 = f2bf(v.w - bf2f(h3));
  ((ushort4*)xhi)[p] = make_ushort4(h0, h1, h2, h3);
  ((ushort4*)xlo)[p] = make_ushort4(l0, l1, l2, l3);
}

// ---------------- K1: squared norms (fp32) ----------------
__global__ __launch_bounds__(256) void sq_kernel(const float* __restrict__ x,
                                                 float* __restrict__ sq) {
  int p = blockIdx.x * 256 + threadIdx.x;
  const float4* xr = (const float4*)(x + (size_t)p * F_);
  float a0 = 0.f, a1 = 0.f, a2 = 0.f, a3 = 0.f;
#pragma unroll
  for (int f = 0; f < 16; ++f) {
    float4 v = xr[f];
    a0 += v.x * v.x; a1 += v.y * v.y; a2 += v.z * v.z; a3 += v.w * v.w;
  }
  sq[p] = (a0 + a1) + (a2 + a3);
}

// ---------------- K2: kNN — MFMA distances + filtered top-24 ----------------
struct Stage {
  ushort bhi[JCH][80];   // 20480 B
  ushort blo[JCH][80];   // 20480 B
  float  sqj[JCH];       // 512 B
};

__global__ __launch_bounds__(256) void knn_kernel(const ushort* __restrict__ xhi,
                                                  const ushort* __restrict__ xlo,
                                                  const float* __restrict__ sq,
                                                  int* __restrict__ cand) {
  __shared__ Stage st;                 // 41472 B
  __shared__ float rowq[ITILE * QSTR]; // 34048 B
  __shared__ int   qcnt[ITILE];        // 256 B
  __shared__ int   thr[ITILE];         // 256 B (packed-float bits)

  const int b = blockIdx.x >> 6;
  const int ib = (blockIdx.x & 63) * ITILE;   // batch-local i base
  const int tid = threadIdx.x;
  const int w = tid >> 6, lane = tid & 63;
  const int hq = lane >> 4, lm = lane & 15;

  // A fragments: wave covers i rows ib + w*16 + lm, K=64 in two halves
  bf16x8 ahi0, ahi1, alo0, alo1;
  {
    const size_t rb = ((size_t)b * N_ + ib + w * 16 + lm) * F_ + hq * 8;
    ahi0 = *(const bf16x8*)(xhi + rb);  ahi1 = *(const bf16x8*)(xhi + rb + 32);
    alo0 = *(const bf16x8*)(xlo + rb);  alo1 = *(const bf16x8*)(xlo + rb + 32);
  }
  const int r0 = w * 16 + hq * 4;      // first of the 4 C-rows this lane owns
  float sqi[4];
#pragma unroll
  for (int r = 0; r < 4; ++r) sqi[r] = sq[b * N_ + ib + r0 + r];

  if (tid < ITILE) thr[tid] = __float_as_int(FLT_MAX);

  const int selrow = tid >> 2, selslot = tid & 3;
  float d[CAND];
#pragma unroll
  for (int k = 0; k < CAND; ++k) d[k] = FLT_MAX;

  for (int jt = 0; jt < N_; jt += JCH) {
    __syncthreads();   // prev processing done; thr/qcnt init visible
    if (tid < ITILE) qcnt[tid] = 0;
    // ---- stage 128 j-rows (hi+lo) + sqj ----
    {
#pragma unroll
      for (int u = 0; u < 4; ++u) {
        int idx = tid + u * 256;
        int jr = idx >> 3, fc = (idx & 7) * 8;
        const size_t src = ((size_t)b * N_ + jt + jr) * F_ + fc;
        *(bf16x8*)&st.bhi[jr][fc] = *(const bf16x8*)(xhi + src);
        *(bf16x8*)&st.blo[jr][fc] = *(const bf16x8*)(xlo + src);
      }
      if (tid < JCH) st.sqj[tid] = sq[b * N_ + jt + tid];
    }
    __syncthreads();

    float thrv[4];
#pragma unroll
    for (int r = 0; r < 4; ++r) thrv[r] = __int_as_float(thr[r0 + r]);

    // ---- MFMA + in-register filter + rare queue append ----
#pragma unroll
    for (int n0 = 0; n0 < 8; ++n0) {
      const ushort* bh = &st.bhi[n0 * 16 + lm][hq * 8];
      const ushort* bl = &st.blo[n0 * 16 + lm][hq * 8];
      bf16x8 bh0 = *(const bf16x8*)(bh);
      bf16x8 bh1 = *(const bf16x8*)(bh + 32);
      bf16x8 bl0 = *(const bf16x8*)(bl);
      bf16x8 bl1 = *(const bf16x8*)(bl + 32);
      f32x4 c = {0.f, 0.f, 0.f, 0.f};
      c = __builtin_amdgcn_mfma_f32_16x16x32_bf16(alo0, bh0, c, 0, 0, 0);
      c = __builtin_amdgcn_mfma_f32_16x16x32_bf16(alo1, bh1, c, 0, 0, 0);
      c = __builtin_amdgcn_mfma_f32_16x16x32_bf16(ahi0, bl0, c, 0, 0, 0);
      c = __builtin_amdgcn_mfma_f32_16x16x32_bf16(ahi1, bl1, c, 0, 0, 0);
      c = __builtin_amdgcn_mfma_f32_16x16x32_bf16(ahi0, bh0, c, 0, 0, 0);
      c = __builtin_amdgcn_mfma_f32_16x16x32_bf16(ahi1, bh1, c, 0, 0, 0);
      const int jg = jt + n0 * 16 + lm;            // batch-local j
      const float sqjv = st.sqj[n0 * 16 + lm];
#pragma unroll
      for (int r = 0; r < 4; ++r) {
        float dd = sqi[r] + sqjv - 2.f * c[r];
        int pvb = (__float_as_int(dd) & (int)0xFFFFF000) | jg;  // pack (d2, j)
        float pv = __int_as_float(pvb);
        bool keep = (pv < thrv[r]) && (ib + r0 + r != jg);
        if (keep) {
          int pos = atomicAdd(&qcnt[r0 + r], 1);
          rowq[(r0 + r) * QSTR + pos] = pv;
        }
      }
    }
    __syncthreads();

    // ---- process queue: 4 owner threads per row ----
    {
      int cn = qcnt[selrow];
      for (int q = selslot; q < cn; q += 4) {
        float pv = rowq[selrow * QSTR + q];
        if (pv < d[CAND - 1]) {
#pragma unroll
          for (int k = CAND - 1; k >= 1; --k) {
            bool sh = pv < d[k - 1];
            bool ins = pv < d[k];
            d[k] = sh ? d[k - 1] : (ins ? pv : d[k]);
          }
          if (pv < d[0]) d[0] = pv;
        }
      }
      atomicMin(&thr[selrow], __float_as_int(d[CAND - 1]));
    }
  }

  __syncthreads();
  // dump sorted packed lists into rowq (dead) for the 4-way merge
#pragma unroll
  for (int k = 0; k < CAND; ++k)
    rowq[selrow * QSTR + selslot * CAND + k] = d[k];
  __syncthreads();

  if (tid < ITILE) {
    const float* base = &rowq[tid * QSTR];
    int* crow = cand + (size_t)(b * N_ + ib + tid) * CAND;
    int p0 = 0, p1 = 0, p2 = 0, p3 = 0;
    for (int k = 0; k < CAND; ++k) {
      float hv = base[p0]; int sm = 0;
      float t;
      t = base[CAND + p1];     if (t < hv) { hv = t; sm = 1; }
      t = base[2 * CAND + p2]; if (t < hv) { hv = t; sm = 2; }
      t = base[3 * CAND + p3]; if (t < hv) { hv = t; sm = 3; }
      crow[k] = __float_as_int(hv) & 0xFFF;   // batch-local j
      p0 += (sm == 0); p1 += (sm == 1); p2 += (sm == 2); p3 += (sm == 3);
    }
  }
}

// ---------------- K2b: fp64 refine of 24 candidates ----------------
__global__ __launch_bounds__(256) void refine_kernel(const float* __restrict__ x,
                                                     const int* __restrict__ cand,
                                                     int* __restrict__ nn) {
  __shared__ double ds[8][CAND];
  __shared__ int    js[8][CAND];
  const int wv = threadIdx.x >> 6, lane = threadIdx.x & 63;
  const int half = lane >> 5, l = lane & 31;   // 2 rows per wave
  const int rl = wv * 2 + half;                // row within block, 0..7
  const int row = blockIdx.x * 8 + rl;
  const int b = row >> 12;

  if (l < CAND) {
    int j = cand[(size_t)row * CAND + l];
    const float* xi = x + (size_t)row * F_;
    const float* xj = x + ((size_t)(b << 12) + j) * F_;
    double s = 0.0;
#pragma unroll
    for (int f = 0; f < F_; ++f) {
      double df = (double)xi[f] - (double)xj[f];
      s = fma(df, df, s);
    }
    ds[rl][l] = s; js[rl][l] = j;
  }
  __syncthreads();
  if (l < CAND) {
    double dm = ds[rl][l]; int jm = js[rl][l];
    int rank = 0;
#pragma unroll
    for (int m = 0; m < CAND; ++m) {
      double dmm = ds[rl][m]; int jmm = js[rl][m];
      rank += (dmm < dm) || (dmm == dm && jmm < jm);
    }
    if (rank < K_) nn[(size_t)row * K_ + rank] = jm;
  }
}

// ---------------- K3: A = X(W1-W2)^T, C = X W2^T ----------------
__global__ __launch_bounds__(256) void feat_kernel(const float* __restrict__ x,
                                                   const float* __restrict__ W,
                                                   float* __restrict__ A,
                                                   float* __restrict__ C) {
  int gid = blockIdx.x * 256 + threadIdx.x;
  int n = gid >> 7;
  int o = gid & 127;
  const float4* xr = (const float4*)(x + (size_t)n * F_);
  float a0 = 0.f, a1 = 0.f, a2 = 0.f, a3 = 0.f;
  if (o < O_) {
    const float4* w1 = (const float4*)(W + (size_t)o * 128);
    const float4* w2 = w1 + 16;
#pragma unroll
    for (int f = 0; f < 16; ++f) {
      float4 xv = xr[f]; float4 u = w1[f]; float4 v = w2[f];
      a0 += xv.x * (u.x - v.x); a1 += xv.y * (u.y - v.y);
      a2 += xv.z * (u.z - v.z); a3 += xv.w * (u.w - v.w);
    }
    A[(size_t)n * O_ + o] = (a0 + a1) + (a2 + a3);
  } else {
    const float4* w2 = (const float4*)(W + (size_t)(o - O_) * 128 + 64);
#pragma unroll
    for (int f = 0; f < 16; ++f) {
      float4 xv = xr[f]; float4 v = w2[f];
      a0 += xv.x * v.x; a1 += xv.y * v.y; a2 += xv.z * v.z; a3 += xv.w * v.w;
    }
    C[(size_t)n * O_ + (o - O_)] = (a0 + a1) + (a2 + a3);
  }
}

// ---------------- K4: gather -> P/Q + per-block BN partials ----------------
__global__ __launch_bounds__(256) void gather_kernel(const int* __restrict__ nn,
                                                     const float* __restrict__ A,
                                                     const float* __restrict__ C,
                                                     const float* __restrict__ bias,
                                                     float* __restrict__ P,
                                                     float* __restrict__ Q,
                                                     float* __restrict__ partial) {
  __shared__ float red[4][2][O_];
  int w = threadIdx.x >> 6;
  int o = threadIdx.x & 63;
  int rowg = blockIdx.x * 4 + w;
  int bb = rowg >> 12;
  const int* nrow = nn + (size_t)rowg * K_;
  float a = A[(size_t)rowg * O_ + o] + bias[o];
  float mx = -FLT_MAX, mn = FLT_MAX, s1 = 0.f, s2 = 0.f;
  for (int k = 0; k < K_; ++k) {
    int j = nrow[k];
    float c = C[((size_t)(bb << 12) + j) * O_ + o];
    mx = fmaxf(mx, c); mn = fminf(mn, c); s1 += c; s2 += c * c;
  }
  P[(size_t)rowg * O_ + o] = a + mx;
  Q[(size_t)rowg * O_ + o] = a + mn;
  red[w][0][o] = 20.f * a + s1;
  red[w][1][o] = 20.f * a * a + 2.f * a * s1 + s2;
  __syncthreads();
  if (w == 0) {
    float ts = red[0][0][o] + red[1][0][o] + red[2][0][o] + red[3][0][o];
    float tq = red[0][1][o] + red[1][1][o] + red[2][1][o] + red[3][1][o];
    partial[(size_t)blockIdx.x * 128 + o] = ts;
    partial[(size_t)blockIdx.x * 128 + 64 + o] = tq;
  }
}

// ---------------- K4b: reduce partials -> sums ----------------
__global__ __launch_bounds__(256) void reduce_kernel(const float* __restrict__ partial,
                                                     float* __restrict__ sums) {
  __shared__ float red[256];
  const int c = blockIdx.x;  // 0..127
  float s = 0.f;
  for (int blk = threadIdx.x; blk < 8192; blk += 256)
    s += partial[(size_t)blk * 128 + c];
  red[threadIdx.x] = s;
  __syncthreads();
  for (int st = 128; st > 0; st >>= 1) {
    if (threadIdx.x < st) red[threadIdx.x] += red[threadIdx.x + st];
    __syncthreads();
  }
  if (threadIdx.x == 0) sums[c] = red[0];
}

// ---------------- K5: finalize BN stats ----------------
__global__ void stats_kernel(const float* __restrict__ sums,
                             const float* __restrict__ gamma,
                             const float* __restrict__ beta,
                             float* __restrict__ sb) {
  int o = threadIdx.x;
  const float cnt = (float)B_ * (float)N_ * (float)K_;
  float mean = sums[o] / cnt;
  float var = sums[O_ + o] / cnt - mean * mean;
  float s = gamma[o] / sqrtf(var + 1e-5f);
  sb[o] = s;
  sb[O_ + o] = beta[o] - mean * s;
}

// ---------------- K6: normalize + relu ----------------
__global__ __launch_bounds__(256) void out_kernel(const float* __restrict__ P,
                                                  const float* __restrict__ Q,
                                                  const float* __restrict__ sb,
                                                  float* __restrict__ out) {
  int gid = blockIdx.x * 256 + threadIdx.x;
  int o = gid & 63;
  float s = sb[o], base = sb[O_ + o];
  float h = (s >= 0.f) ? P[gid] : Q[gid];
  float z = h * s + base;
  out[gid] = z > 0.f ? z : 0.f;
}

extern "C" void kernel_launch(void* const* d_in, const int* in_sizes, int n_in,
                              void* d_out, int out_size, void* d_ws, size_t ws_size,
                              hipStream_t stream) {
  const float* x     = (const float*)d_in[0];
  const float* W     = (const float*)d_in[1];
  const float* bias  = (const float*)d_in[2];
  const float* gamma = (const float*)d_in[3];
  const float* beta  = (const float*)d_in[4];
  float* out = (float*)d_out;

  char* ws = (char*)d_ws;
  size_t off = 0;
  auto alloc = [&](size_t bytes) -> void* {
    void* p = ws + off;
    off += (bytes + 255) & ~(size_t)255;
    return p;
  };
  ushort* xhi    = (ushort*)alloc(sizeof(ushort) * (size_t)B_ * N_ * F_);
  ushort* xlo    = (ushort*)alloc(sizeof(ushort) * (size_t)B_ * N_ * F_);
  float* sq      = (float*)alloc(sizeof(float) * (size_t)B_ * N_);
  int*   cand    = (int*)  alloc(sizeof(int)   * (size_t)B_ * N_ * CAND);
  int*   nn      = (int*)  alloc(sizeof(int)   * (size_t)B_ * N_ * K_);
  float* A       = (float*)alloc(sizeof(float) * (size_t)B_ * N_ * O_);
  float* C       = (float*)alloc(sizeof(float) * (size_t)B_ * N_ * O_);
  float* P       = (float*)alloc(sizeof(float) * (size_t)B_ * N_ * O_);
  float* Q       = (float*)alloc(sizeof(float) * (size_t)B_ * N_ * O_);
  float* partial = (float*)alloc(sizeof(float) * 8192 * 128);
  float* sums    = (float*)alloc(sizeof(float) * 2 * O_);
  float* sb      = (float*)alloc(sizeof(float) * 2 * O_);

  cvt_kernel   <<<(B_ * N_ * F_ / 4) / 256, 256, 0, stream>>>(x, xhi, xlo);
  sq_kernel    <<<(B_ * N_) / 256, 256, 0, stream>>>(x, sq);
  knn_kernel   <<<B_ * (N_ / ITILE), 256, 0, stream>>>(xhi, xlo, sq, cand);
  refine_kernel<<<(B_ * N_) / 8, 256, 0, stream>>>(x, cand, nn);
  feat_kernel  <<<(B_ * N_ * 128) / 256, 256, 0, stream>>>(x, W, A, C);
  gather_kernel<<<(B_ * N_) / 4, 256, 0, stream>>>(nn, A, C, bias, P, Q, partial);
  reduce_kernel<<<128, 256, 0, stream>>>(partial, sums);
  stats_kernel <<<1, 64, 0, stream>>>(sums, gamma, beta, sb);
  out_kernel   <<<(B_ * N_ * O_) / 256, 256, 0, stream>>>(P, Q, sb, out);
}

// Round 5
// 544.372 us; speedup vs baseline: 3.4114x; 1.0061x over previous
//
#include <hip/hip_runtime.h>
#include <cfloat>
#include <math.h>

#define B_ 8
#define N_ 4096
#define F_ 64
#define O_ 64
#define K_ 20
#define CAND 24
#define ITILE 64      // i-rows per block
#define JCH 128       // j-chunk per iteration
#define BSTR 72       // ushort stride of staged rows: 144 B = 36 banks (== 4 mod 32 -> 2-way, free)
#define QSTR 133      // rowq stride in floats

typedef __attribute__((ext_vector_type(8))) short bf16x8;
typedef __attribute__((ext_vector_type(16))) float f32x16;

__device__ __forceinline__ ushort f2bf(float f) {
  unsigned u = __float_as_uint(f);
  u += 0x7FFF + ((u >> 16) & 1);   // round-to-nearest-even
  return (ushort)(u >> 16);
}
__device__ __forceinline__ float bf2f(ushort h) {
  return __uint_as_float(((unsigned)h) << 16);
}

// ---------------- K0: split x into bf16 hi/lo ----------------
__global__ __launch_bounds__(256) void cvt_kernel(const float* __restrict__ x,
                                                  ushort* __restrict__ xhi,
                                                  ushort* __restrict__ xlo) {
  int p = blockIdx.x * 256 + threadIdx.x;
  float4 v = ((const float4*)x)[p];
  ushort h0 = f2bf(v.x), h1 = f2bf(v.y), h2 = f2bf(v.z), h3 = f2bf(v.w);
  ushort l0 = f2bf(v.x - bf2f(h0)), l1 = f2bf(v.y - bf2f(h1));
  ushort l2 = f2bf(v.z - bf2f(h2)), l3 = f2bf(v.w - bf2f(h3));
  ((ushort4*)xhi)[p] = make_ushort4(h0, h1, h2, h3);
  ((ushort4*)xlo)[p] = make_ushort4(l0, l1, l2, l3);
}

// ---------------- K1: squared norms (fp32) ----------------
__global__ __launch_bounds__(256) void sq_kernel(const float* __restrict__ x,
                                                 float* __restrict__ sq) {
  int p = blockIdx.x * 256 + threadIdx.x;
  const float4* xr = (const float4*)(x + (size_t)p * F_);
  float a0 = 0.f, a1 = 0.f, a2 = 0.f, a3 = 0.f;
#pragma unroll
  for (int f = 0; f < 16; ++f) {
    float4 v = xr[f];
    a0 += v.x * v.x; a1 += v.y * v.y; a2 += v.z * v.z; a3 += v.w * v.w;
  }
  sq[p] = (a0 + a1) + (a2 + a3);
}

// ---------------- K2: kNN — 32x32 MFMA distances + filtered top-24 ----------------
struct Stage {
  ushort bhi[JCH][BSTR];   // 18432 B
  ushort blo[JCH][BSTR];   // 18432 B
  float  sqj[JCH];         // 512 B
};

// MODE: 0 = dense (chunk 0; self-check on; no filter/atomics)
//       1 = filter + self-check   2 = filter, no self
template <int MODE>
__device__ __forceinline__ void knn_tile(int jt, int tj, int ib, int l31, int lh,
                                         int irbase,
                                         const bf16x8* ahi, const bf16x8* alo,
                                         const float* sqi, const float* thrv,
                                         Stage& st, float* rowq, int* qcnt) {
  const ushort* bph = &st.bhi[tj + l31][lh * 8];
  const ushort* bpl = &st.blo[tj + l31][lh * 8];
  bf16x8 bh[4], bl[4];
#pragma unroll
  for (int kk = 0; kk < 4; ++kk) {
    bh[kk] = *(const bf16x8*)(bph + kk * 16);
    bl[kk] = *(const bf16x8*)(bpl + kk * 16);
  }
  f32x16 c = {0.f, 0.f, 0.f, 0.f, 0.f, 0.f, 0.f, 0.f,
              0.f, 0.f, 0.f, 0.f, 0.f, 0.f, 0.f, 0.f};
#pragma unroll
  for (int kk = 0; kk < 4; ++kk) c = __builtin_amdgcn_mfma_f32_32x32x16_bf16(alo[kk], bh[kk], c, 0, 0, 0);
#pragma unroll
  for (int kk = 0; kk < 4; ++kk) c = __builtin_amdgcn_mfma_f32_32x32x16_bf16(ahi[kk], bl[kk], c, 0, 0, 0);
#pragma unroll
  for (int kk = 0; kk < 4; ++kk) c = __builtin_amdgcn_mfma_f32_32x32x16_bf16(ahi[kk], bh[kk], c, 0, 0, 0);

  const int jg = jt + tj + l31;                 // batch-local j
  const float sqjv = st.sqj[tj + l31];
#pragma unroll
  for (int r = 0; r < 16; ++r) {
    const int cr = (r & 3) + 8 * (r >> 2);      // C/D row pattern (32x32)
    const int ir = irbase + cr;                 // local i-row 0..63
    float dd = fmaf(-2.f, c[r], sqi[r] + sqjv);
    int pvb = (__float_as_int(dd) & (int)0xFFFFF000) | jg;
    float pv = __int_as_float(pvb);
    if (MODE <= 1 && (ib + ir == jg)) pv = __int_as_float(0x7F700000 | jg);
    if (MODE == 0) {
      rowq[ir * QSTR + tj + l31] = pv;          // dense: slot = j
    } else {
      if (pv < thrv[r]) {
        int pos = atomicAdd(&qcnt[ir], 1);
        rowq[ir * QSTR + pos] = pv;
      }
    }
  }
}

__global__ __launch_bounds__(256) void knn_kernel(const ushort* __restrict__ xhi,
                                                  const ushort* __restrict__ xlo,
                                                  const float* __restrict__ sq,
                                                  int* __restrict__ cand) {
  __shared__ Stage st;                  // 37376 B
  __shared__ float rowq[ITILE * QSTR]; // 34048 B
  __shared__ int   qcnt[ITILE];
  __shared__ int   thr[ITILE];

  const int b = blockIdx.x >> 6;
  const int ib = (blockIdx.x & 63) * ITILE;  // batch-local i base
  const int tid = threadIdx.x;
  const int w = tid >> 6, lane = tid & 63;
  const int iw = w & 1;                 // i-half (rows iw*32..+31)
  const int jh = w >> 1;                // j-half (cols jh*64..+63)
  const int l31 = lane & 31, lh = lane >> 5;
  const int irbase = iw * 32 + 4 * lh;

  // A fragments: row = ib + iw*32 + l31, k = lh*8 + kk*16 + (0..7)
  bf16x8 ahi[4], alo[4];
  {
    const size_t ar = ((size_t)b * N_ + ib + iw * 32 + l31) * F_ + lh * 8;
#pragma unroll
    for (int kk = 0; kk < 4; ++kk) {
      ahi[kk] = *(const bf16x8*)(xhi + ar + kk * 16);
      alo[kk] = *(const bf16x8*)(xlo + ar + kk * 16);
    }
  }
  float sqi[16];
#pragma unroll
  for (int r = 0; r < 16; ++r)
    sqi[r] = sq[b * N_ + ib + irbase + (r & 3) + 8 * (r >> 2)];

  if (tid < ITILE) thr[tid] = __float_as_int(FLT_MAX);

  const int selrow = tid >> 2, selslot = tid & 3;
  float d[CAND];
#pragma unroll
  for (int k = 0; k < CAND; ++k) d[k] = FLT_MAX;

  for (int jt = 0; jt < N_; jt += JCH) {
    __syncthreads();   // prev queue processing done
    if (tid < ITILE) qcnt[tid] = (jt == 0) ? JCH : 0;
    // ---- stage 128 j-rows (hi+lo) + sqj ----
#pragma unroll
    for (int u = 0; u < 4; ++u) {
      int idx = tid + u * 256;
      int jr = idx >> 3, fc = (idx & 7) * 8;
      const size_t src = ((size_t)b * N_ + jt + jr) * F_ + fc;
      *(bf16x8*)&st.bhi[jr][fc] = *(const bf16x8*)(xhi + src);
      *(bf16x8*)&st.blo[jr][fc] = *(const bf16x8*)(xlo + src);
    }
    if (tid < JCH) st.sqj[tid] = sq[b * N_ + jt + tid];
    __syncthreads();

    float thrv[16];
    if (jt == 0) {
      knn_tile<0>(jt, jh * 64,      ib, l31, lh, irbase, ahi, alo, sqi, thrv, st, rowq, qcnt);
      knn_tile<0>(jt, jh * 64 + 32, ib, l31, lh, irbase, ahi, alo, sqi, thrv, st, rowq, qcnt);
    } else {
#pragma unroll
      for (int r = 0; r < 16; ++r)
        thrv[r] = __int_as_float(thr[irbase + (r & 3) + 8 * (r >> 2)]);
      if (jt == (ib & ~(JCH - 1))) {
        knn_tile<1>(jt, jh * 64,      ib, l31, lh, irbase, ahi, alo, sqi, thrv, st, rowq, qcnt);
        knn_tile<1>(jt, jh * 64 + 32, ib, l31, lh, irbase, ahi, alo, sqi, thrv, st, rowq, qcnt);
      } else {
        knn_tile<2>(jt, jh * 64,      ib, l31, lh, irbase, ahi, alo, sqi, thrv, st, rowq, qcnt);
        knn_tile<2>(jt, jh * 64 + 32, ib, l31, lh, irbase, ahi, alo, sqi, thrv, st, rowq, qcnt);
      }
    }
    __syncthreads();

    // ---- process queue: 4 owner threads per row ----
    {
      int cn = qcnt[selrow];
      for (int q = selslot; q < cn; q += 4) {
        float pv = rowq[selrow * QSTR + q];
        if (pv < d[CAND - 1]) {
#pragma unroll
          for (int k = CAND - 1; k >= 1; --k) {
            bool sh = pv < d[k - 1];
            bool ins = pv < d[k];
            d[k] = sh ? d[k - 1] : (ins ? pv : d[k]);
          }
          if (pv < d[0]) d[0] = pv;
        }
      }
      atomicMin(&thr[selrow], __float_as_int(d[CAND - 1]));
    }
  }

  __syncthreads();
#pragma unroll
  for (int k = 0; k < CAND; ++k)
    rowq[selrow * QSTR + selslot * CAND + k] = d[k];
  __syncthreads();

  if (tid < ITILE) {
    const float* base = &rowq[tid * QSTR];
    int* crow = cand + (size_t)(b * N_ + ib + tid) * CAND;
    int p0 = 0, p1 = 0, p2 = 0, p3 = 0;
    for (int k = 0; k < CAND; ++k) {
      float hv = base[p0]; int sm = 0;
      float t;
      t = base[CAND + p1];     if (t < hv) { hv = t; sm = 1; }
      t = base[2 * CAND + p2]; if (t < hv) { hv = t; sm = 2; }
      t = base[3 * CAND + p3]; if (t < hv) { hv = t; sm = 3; }
      crow[k] = __float_as_int(hv) & 0xFFF;
      p0 += (sm == 0); p1 += (sm == 1); p2 += (sm == 2); p3 += (sm == 3);
    }
  }
}

// ---------------- K2b: fp64 refine — one lane per (row, candidate) ----------------
__global__ __launch_bounds__(256) void refine_kernel(const float* __restrict__ x,
                                                     const int* __restrict__ cand,
                                                     int* __restrict__ nn) {
  __shared__ double ds[8][CAND];
  __shared__ int    js[8][CAND];
  const int w = threadIdx.x >> 6, lane = threadIdx.x & 63;
  const int half = lane >> 5, c = lane & 31;
  const int rl = w * 2 + half;             // row within block 0..7
  const int row = blockIdx.x * 8 + rl;
  const int b = row >> 12;

  if (c < CAND) {
    int j = cand[(size_t)row * CAND + c];
    const float4* xi4 = (const float4*)(x + (size_t)row * F_);
    const float4* xj4 = (const float4*)(x + ((size_t)(b << 12) + j) * F_);
    double s = 0.0;
#pragma unroll
    for (int u = 0; u < 16; ++u) {
      float4 a = xi4[u], v = xj4[u];
      double d0 = (double)a.x - (double)v.x;
      double d1 = (double)a.y - (double)v.y;
      double d2 = (double)a.z - (double)v.z;
      double d3 = (double)a.w - (double)v.w;
      s = fma(d0, d0, s); s = fma(d1, d1, s);
      s = fma(d2, d2, s); s = fma(d3, d3, s);
    }
    ds[rl][c] = s; js[rl][c] = j;
  }
  __syncthreads();
  if (c < CAND) {
    double dm = ds[rl][c]; int jm = js[rl][c];
    int rank = 0;
#pragma unroll
    for (int m = 0; m < CAND; ++m) {
      double dmm = ds[rl][m]; int jmm = js[rl][m];
      rank += (dmm < dm) || (dmm == dm && jmm < jm);
    }
    if (rank < K_) nn[(size_t)row * K_ + rank] = jm;
  }
}

// ---------------- K3: A = X(W1-W2)^T, C = X W2^T ----------------
__global__ __launch_bounds__(256) void feat_kernel(const float* __restrict__ x,
                                                   const float* __restrict__ W,
                                                   float* __restrict__ A,
                                                   float* __restrict__ C) {
  int gid = blockIdx.x * 256 + threadIdx.x;
  int n = gid >> 7;
  int o = gid & 127;
  const float4* xr = (const float4*)(x + (size_t)n * F_);
  float a0 = 0.f, a1 = 0.f, a2 = 0.f, a3 = 0.f;
  if (o < O_) {
    const float4* w1 = (const float4*)(W + (size_t)o * 128);
    const float4* w2 = w1 + 16;
#pragma unroll
    for (int f = 0; f < 16; ++f) {
      float4 xv = xr[f]; float4 u = w1[f]; float4 v = w2[f];
      a0 += xv.x * (u.x - v.x); a1 += xv.y * (u.y - v.y);
      a2 += xv.z * (u.z - v.z); a3 += xv.w * (u.w - v.w);
    }
    A[(size_t)n * O_ + o] = (a0 + a1) + (a2 + a3);
  } else {
    const float4* w2 = (const float4*)(W + (size_t)(o - O_) * 128 + 64);
#pragma unroll
    for (int f = 0; f < 16; ++f) {
      float4 xv = xr[f]; float4 v = w2[f];
      a0 += xv.x * v.x; a1 += xv.y * v.y; a2 += xv.z * v.z; a3 += xv.w * v.w;
    }
    C[(size_t)n * O_ + (o - O_)] = (a0 + a1) + (a2 + a3);
  }
}

// ---------------- K4: gather -> P/Q + per-block BN partials ----------------
__global__ __launch_bounds__(256) void gather_kernel(const int* __restrict__ nn,
                                                     const float* __restrict__ A,
                                                     const float* __restrict__ C,
                                                     const float* __restrict__ bias,
                                                     float* __restrict__ P,
                                                     float* __restrict__ Q,
                                                     float* __restrict__ partial) {
  __shared__ float red[4][2][O_];
  int w = threadIdx.x >> 6;
  int o = threadIdx.x & 63;
  int rowg = blockIdx.x * 4 + w;
  int bb = rowg >> 12;
  const int* nrow = nn + (size_t)rowg * K_;
  float a = A[(size_t)rowg * O_ + o] + bias[o];
  float mx = -FLT_MAX, mn = FLT_MAX, s1 = 0.f, s2 = 0.f;
  for (int k = 0; k < K_; ++k) {
    int j = nrow[k];
    float c = C[((size_t)(bb << 12) + j) * O_ + o];
    mx = fmaxf(mx, c); mn = fminf(mn, c); s1 += c; s2 += c * c;
  }
  P[(size_t)rowg * O_ + o] = a + mx;
  Q[(size_t)rowg * O_ + o] = a + mn;
  red[w][0][o] = 20.f * a + s1;
  red[w][1][o] = 20.f * a * a + 2.f * a * s1 + s2;
  __syncthreads();
  if (w == 0) {
    float ts = red[0][0][o] + red[1][0][o] + red[2][0][o] + red[3][0][o];
    float tq = red[0][1][o] + red[1][1][o] + red[2][1][o] + red[3][1][o];
    partial[(size_t)blockIdx.x * 128 + o] = ts;
    partial[(size_t)blockIdx.x * 128 + 64 + o] = tq;
  }
}

// ---------------- K4b: coalesced partial reduction (stage 1) ----------------
__global__ __launch_bounds__(256) void reduce1_kernel(const float* __restrict__ partial,
                                                      float* __restrict__ partial2) {
  __shared__ float red[2][128];
  int c = threadIdx.x & 127, rq = threadIdx.x >> 7;
  int base = blockIdx.x * 128;
  float s = 0.f;
  for (int i = 0; i < 64; ++i)
    s += partial[(size_t)(base + rq + 2 * i) * 128 + c];
  red[rq][c] = s;
  __syncthreads();
  if (rq == 0) partial2[(size_t)blockIdx.x * 128 + c] = red[0][c] + red[1][c];
}

// ---------------- K5: stage-2 reduce + finalize BN stats ----------------
__global__ void stats_kernel(const float* __restrict__ partial2,
                             const float* __restrict__ gamma,
                             const float* __restrict__ beta,
                             float* __restrict__ sb) {
  __shared__ float sall[128];
  int c = threadIdx.x;  // 128 threads
  float s = 0.f;
  for (int blk = 0; blk < 64; ++blk) s += partial2[(size_t)blk * 128 + c];
  sall[c] = s;
  __syncthreads();
  if (c < 64) {
    const float cnt = (float)B_ * (float)N_ * (float)K_;
    float mean = sall[c] / cnt;
    float var = sall[64 + c] / cnt - mean * mean;
    float sc = gamma[c] / sqrtf(var + 1e-5f);
    sb[c] = sc;
    sb[64 + c] = beta[c] - mean * sc;
  }
}

// ---------------- K6: normalize + relu ----------------
__global__ __launch_bounds__(256) void out_kernel(const float* __restrict__ P,
                                                  const float* __restrict__ Q,
                                                  const float* __restrict__ sb,
                                                  float* __restrict__ out) {
  int gid = blockIdx.x * 256 + threadIdx.x;
  int o = gid & 63;
  float s = sb[o], base = sb[O_ + o];
  float h = (s >= 0.f) ? P[gid] : Q[gid];
  float z = h * s + base;
  out[gid] = z > 0.f ? z : 0.f;
}

extern "C" void kernel_launch(void* const* d_in, const int* in_sizes, int n_in,
                              void* d_out, int out_size, void* d_ws, size_t ws_size,
                              hipStream_t stream) {
  const float* x     = (const float*)d_in[0];
  const float* W     = (const float*)d_in[1];
  const float* bias  = (const float*)d_in[2];
  const float* gamma = (const float*)d_in[3];
  const float* beta  = (const float*)d_in[4];
  float* out = (float*)d_out;

  char* ws = (char*)d_ws;
  size_t off = 0;
  auto alloc = [&](size_t bytes) -> void* {
    void* p = ws + off;
    off += (bytes + 255) & ~(size_t)255;
    return p;
  };
  ushort* xhi     = (ushort*)alloc(sizeof(ushort) * (size_t)B_ * N_ * F_);
  ushort* xlo     = (ushort*)alloc(sizeof(ushort) * (size_t)B_ * N_ * F_);
  float* sq       = (float*)alloc(sizeof(float) * (size_t)B_ * N_);
  int*   cand     = (int*)  alloc(sizeof(int)   * (size_t)B_ * N_ * CAND);
  int*   nn       = (int*)  alloc(sizeof(int)   * (size_t)B_ * N_ * K_);
  float* A        = (float*)alloc(sizeof(float) * (size_t)B_ * N_ * O_);
  float* C        = (float*)alloc(sizeof(float) * (size_t)B_ * N_ * O_);
  float* P        = (float*)alloc(sizeof(float) * (size_t)B_ * N_ * O_);
  float* Q        = (float*)alloc(sizeof(float) * (size_t)B_ * N_ * O_);
  float* partial  = (float*)alloc(sizeof(float) * 8192 * 128);
  float* partial2 = (float*)alloc(sizeof(float) * 64 * 128);
  float* sb       = (float*)alloc(sizeof(float) * 2 * O_);

  cvt_kernel    <<<(B_ * N_ * F_ / 4) / 256, 256, 0, stream>>>(x, xhi, xlo);
  sq_kernel     <<<(B_ * N_) / 256, 256, 0, stream>>>(x, sq);
  knn_kernel    <<<B_ * (N_ / ITILE), 256, 0, stream>>>(xhi, xlo, sq, cand);
  refine_kernel <<<(B_ * N_) / 8, 256, 0, stream>>>(x, cand, nn);
  feat_kernel   <<<(B_ * N_ * 128) / 256, 256, 0, stream>>>(x, W, A, C);
  gather_kernel <<<(B_ * N_) / 4, 256, 0, stream>>>(nn, A, C, bias, P, Q, partial);
  reduce1_kernel<<<64, 256, 0, stream>>>(partial, partial2);
  stats_kernel  <<<1, 128, 0, stream>>>(partial2, gamma, beta, sb);
  out_kernel    <<<(B_ * N_ * O_) / 256, 256, 0, stream>>>(P, Q, sb, out);
}